// Round 1
// baseline (52.407 us; speedup 1.0000x reference)
//
#include <hip/hip_runtime.h>
#include <math.h>

// NEG_INF = -2^32+1 (rounds to -4294967296.0f in fp32, same as the reference's cast)
#define NEG_INF_F (-4294967295.0f)

constexpr int B_ = 128;
constexpr int T_ = 8192;
constexpr int U_ = 64;
constexpr int NCHUNK = 8;            // T-chunks per batch in the weighted-sum kernel
constexpr int CHUNK  = T_ / NCHUNK;  // 1024 rows per block

// ---------------------------------------------------------------------------
// Kernel 1: per-batch masked softmax -> normalized weights w[b][t] in d_ws.
// One 1024-thread block per batch; each thread owns 8 contiguous elements
// (two float4 / int4 loads -> fully coalesced 2KB per wave).
// ---------------------------------------------------------------------------
__global__ __launch_bounds__(1024) void k_weights(const float* __restrict__ align,
                                                  const int* __restrict__ mask,
                                                  float* __restrict__ w) {
  const int b   = blockIdx.x;
  const int tid = threadIdx.x;
  const size_t base = (size_t)b * T_;
  const float4* a4 = (const float4*)(align + base);
  const int4*   m4 = (const int4*)(mask + base);
  float4*       w4 = (float4*)(w + base);

  float4 av0 = a4[tid * 2 + 0];
  float4 av1 = a4[tid * 2 + 1];
  int4   mv0 = m4[tid * 2 + 0];
  int4   mv1 = m4[tid * 2 + 1];

  float sc[8];
  sc[0] = mv0.x ? av0.x : NEG_INF_F;
  sc[1] = mv0.y ? av0.y : NEG_INF_F;
  sc[2] = mv0.z ? av0.z : NEG_INF_F;
  sc[3] = mv0.w ? av0.w : NEG_INF_F;
  sc[4] = mv1.x ? av1.x : NEG_INF_F;
  sc[5] = mv1.y ? av1.y : NEG_INF_F;
  sc[6] = mv1.z ? av1.z : NEG_INF_F;
  sc[7] = mv1.w ? av1.w : NEG_INF_F;

  float lmax = sc[0];
#pragma unroll
  for (int i = 1; i < 8; i++) lmax = fmaxf(lmax, sc[i]);
#pragma unroll
  for (int off = 32; off > 0; off >>= 1) lmax = fmaxf(lmax, __shfl_xor(lmax, off));

  __shared__ float red[16];
  __shared__ float s_m, s_invl;
  const int wave = tid >> 6;
  if ((tid & 63) == 0) red[wave] = lmax;
  __syncthreads();
  if (tid < 16) {
    float v = red[tid];
#pragma unroll
    for (int off = 8; off > 0; off >>= 1) v = fmaxf(v, __shfl_xor(v, off));
    if (tid == 0) s_m = v;
  }
  __syncthreads();
  const float m = s_m;

  float e[8];
  float lsum = 0.f;
#pragma unroll
  for (int i = 0; i < 8; i++) { e[i] = __expf(sc[i] - m); lsum += e[i]; }
#pragma unroll
  for (int off = 32; off > 0; off >>= 1) lsum += __shfl_xor(lsum, off);
  if ((tid & 63) == 0) red[wave] = lsum;
  __syncthreads();
  if (tid < 16) {
    float v = red[tid];
#pragma unroll
    for (int off = 8; off > 0; off >>= 1) v += __shfl_xor(v, off);
    if (tid == 0) s_invl = 1.0f / v;
  }
  __syncthreads();
  const float invl = s_invl;

  w4[tid * 2 + 0] = make_float4(e[0] * invl, e[1] * invl, e[2] * invl, e[3] * invl);
  w4[tid * 2 + 1] = make_float4(e[4] * invl, e[5] * invl, e[6] * invl, e[7] * invl);
}

// ---------------------------------------------------------------------------
// Kernel 2: the 256 MiB stream. Block = (batch, chunk of 1024 rows).
// 256 threads = 16 row-groups x 16 lanes; each lane holds a float4 (4 U's),
// so one iteration reads 16 rows x 256B = 4KB fully coalesced.
// Partial sums go to ws (deterministic — no atomics).
// ---------------------------------------------------------------------------
__global__ __launch_bounds__(256) void k_wsum(const float* __restrict__ value,
                                              const float* __restrict__ w,
                                              float* __restrict__ partial) {
  const int b     = blockIdx.x / NCHUNK;
  const int chunk = blockIdx.x % NCHUNK;
  const int tid   = threadIdx.x;
  const int grp   = tid >> 4;   // row within the 16-row slab
  const int lane  = tid & 15;   // which float4 of the 64-float row
  const float4* v4 = (const float4*)(value + (size_t)b * T_ * U_);
  const float*  wb = w + (size_t)b * T_;
  const int t0 = chunk * CHUNK;

  float4 acc = make_float4(0.f, 0.f, 0.f, 0.f);
#pragma unroll 4
  for (int it = 0; it < CHUNK / 16; ++it) {
    const int t = t0 + it * 16 + grp;
    const float wt = wb[t];                       // broadcast across 16 lanes
    const float4 v = v4[(size_t)t * 16 + lane];
    acc.x += wt * v.x;
    acc.y += wt * v.y;
    acc.z += wt * v.z;
    acc.w += wt * v.w;
  }

  __shared__ float4 lds[16][16];
  lds[grp][lane] = acc;
  __syncthreads();
#pragma unroll
  for (int s = 8; s > 0; s >>= 1) {
    if (grp < s) {
      float4 o = lds[grp + s][lane];
      acc.x += o.x; acc.y += o.y; acc.z += o.z; acc.w += o.w;
      lds[grp][lane] = acc;
    }
    __syncthreads();
  }
  if (grp == 0) {
    float4* p = (float4*)(partial + ((size_t)b * NCHUNK + chunk) * U_);
    p[lane] = acc;
  }
}

// ---------------------------------------------------------------------------
// Kernel 3: reduce the NCHUNK partials per (b,u) -> out.
// ---------------------------------------------------------------------------
__global__ __launch_bounds__(256) void k_final(const float* __restrict__ partial,
                                               float* __restrict__ out) {
  const int idx = blockIdx.x * blockDim.x + threadIdx.x;  // 0 .. B*U-1
  const int b = idx / U_;
  const int u = idx % U_;
  const float* p = partial + (size_t)b * NCHUNK * U_ + u;
  float s = 0.f;
#pragma unroll
  for (int c = 0; c < NCHUNK; ++c) s += p[c * U_];
  out[idx] = s;
}

extern "C" void kernel_launch(void* const* d_in, const int* in_sizes, int n_in,
                              void* d_out, int out_size, void* d_ws, size_t ws_size,
                              hipStream_t stream) {
  const float* align = (const float*)d_in[0];
  const float* value = (const float*)d_in[1];
  const int*   mask  = (const int*)d_in[2];
  float* out = (float*)d_out;

  float* w       = (float*)d_ws;              // B*T floats = 4 MiB
  float* partial = w + (size_t)B_ * T_;       // B*NCHUNK*U floats = 256 KiB

  k_weights<<<B_, 1024, 0, stream>>>(align, mask, w);
  k_wsum<<<B_ * NCHUNK, 256, 0, stream>>>(value, w, partial);
  k_final<<<(B_ * U_) / 256, 256, 0, stream>>>(partial, out);
}